// Round 16
// baseline (67.979 us; speedup 1.0000x reference)
//
#include <hip/hip_runtime.h>
#include <math.h>

// Capsule dynamic routing v17 — split; K1 occupancy+MLP fix, K2 unchanged.
// R15: K2's single-barrier form hit ~15us (done). K1 stuck at ~46us:
// 720 blocks = 2.8/CU (grid-limited ~11 waves/CU, tail) + serial
// xload->FMA->store chain exposing ~300cyc L2 latency each of 32 iters.
// v17 K1: BBLK 32->16 (1440 blocks, ~22 waves/CU queued; W re-reads rise
// to 92MB but W unique is 7.4MB = L2-served) + 1-deep x prefetch.
// Write-BW floor for the 92MB fp16 P is ~29us; that's the target.
//
// x: [B=256, R=1152, I=8] f32 ; W: [C=10, R=1152, I=8, O=16] f32
// out: [B=256, C=10, O=16] f32 ; P(ws): [C][B][R][O] fp16

#define C_CAPS 10
#define B_SZ   256
#define R_SZ   1152
#define I_SZ   8
#define O_SZ   16

static __device__ __forceinline__ unsigned int pack2h(float a, float b) {
    const _Float16 ha = (_Float16)a, hb = (_Float16)b;
    const unsigned short ua = __builtin_bit_cast(unsigned short, ha);
    const unsigned short ub = __builtin_bit_cast(unsigned short, hb);
    return (unsigned int)ua | ((unsigned int)ub << 16);
}
static __device__ __forceinline__ float h2f(unsigned short u) {
    const _Float16 h = __builtin_bit_cast(_Float16, u);
    return (float)h;
}

// ---------------- K1: priors ----------------
// grid: C * (R/128=9) * (B/16=16) = 1440 blocks, 256 threads.
// thread t: rl = t>>1 (row 0..127), oh = t&1 (o-half). Loops 16 batches
// with 1-deep x prefetch.
#define RTILE 128
#define BBLK  16
__global__ __launch_bounds__(256, 1) void priors_kernel(
    const float* __restrict__ x,
    const float* __restrict__ w,
    unsigned short* __restrict__ P)
{
    const int bid = blockIdx.x;
    const int c   = bid / 144;            // 144 = 9 rtiles * 16 bgroups
    const int rem = bid - c * 144;
    const int rt  = rem >> 4;             // row tile 0..8
    const int bg  = rem & 15;             // b group 0..15
    const int t   = (int)threadIdx.x;
    const int rl  = t >> 1;               // 0..127
    const int oh  = t & 1;                // o-half
    const int r   = rt * RTILE + rl;
    const int b0  = bg * BBLK;

    // one-time W load: W[c][r][i][oh*8 .. +7] -> 64 regs
    const float* wb = w + (((size_t)c * R_SZ + r) * I_SZ) * O_SZ + oh * 8;
    float W0[I_SZ][8];
    #pragma unroll
    for (int i = 0; i < I_SZ; ++i) {
        const float4 a = *(const float4*)(wb + i * O_SZ);
        const float4 bv = *(const float4*)(wb + i * O_SZ + 4);
        W0[i][0] = a.x;  W0[i][1] = a.y;  W0[i][2] = a.z;  W0[i][3] = a.w;
        W0[i][4] = bv.x; W0[i][5] = bv.y; W0[i][6] = bv.z; W0[i][7] = bv.w;
    }

    const float* xr = x + ((size_t)b0 * R_SZ + r) * I_SZ;
    unsigned int* pr = (unsigned int*)
        (P + (((size_t)c * B_SZ + b0) * R_SZ + r) * O_SZ + oh * 8);
    const size_t xstep = (size_t)R_SZ * I_SZ;        // floats per b
    const size_t pstep = (size_t)R_SZ * O_SZ / 2;    // uints per b

    // prefetch b=0's x
    float4 xa = *(const float4*)(xr);
    float4 xb = *(const float4*)(xr + 4);

    for (int bb = 0; bb < BBLK; ++bb) {
        float4 na, nb;
        if (bb < BBLK - 1) {                          // issue next-b x loads
            na = *(const float4*)(xr + xstep);
            nb = *(const float4*)(xr + xstep + 4);
        }
        const float xi[I_SZ] = {xa.x, xa.y, xa.z, xa.w, xb.x, xb.y, xb.z, xb.w};
        float acc[8];
        #pragma unroll
        for (int k = 0; k < 8; ++k) acc[k] = 0.0f;
        #pragma unroll
        for (int i = 0; i < I_SZ; ++i) {
            #pragma unroll
            for (int k = 0; k < 8; ++k)
                acc[k] = fmaf(xi[i], W0[i][k], acc[k]);
        }
        uint4 o;
        o.x = pack2h(acc[0], acc[1]);
        o.y = pack2h(acc[2], acc[3]);
        o.z = pack2h(acc[4], acc[5]);
        o.w = pack2h(acc[6], acc[7]);
        *(uint4*)pr = o;                 // 16B/lane -> 1KB/wave-inst contiguous
        if (bb < BBLK - 1) { xa = na; xb = nb; }
        xr += xstep;
        pr += pstep;
    }
}

// ---------------- K2: routing (v16, proven ~15us) ----------------
// One block per (c,b). 512 threads = 128 groups of 4 lanes; 8 waves.
#define T2 512
#define NGROUP 128
#define RPT 9
#define NW 8

__global__ __launch_bounds__(T2, 1) void routing_kernel(
    const unsigned short* __restrict__ P,
    float* __restrict__ out)
{
    const int c = blockIdx.x >> 8;
    const int b = blockIdx.x & 255;
    const int t = (int)threadIdx.x;
    const int lane = t & 63;
    const int wid = t >> 6;
    const int q = t & 3;
    const int g = t >> 2;

    __shared__ float4 red_s[2][NW][4];   // double-buffered by iter parity
    __shared__ float  red_z[2][NW];

    const unsigned short* pbase =
        P + (((size_t)c * B_SZ + b) * R_SZ + g) * O_SZ + q * 4;
    float Pr[RPT][4];
    #pragma unroll
    for (int j = 0; j < RPT; ++j) {
        const ushort4 pv = *(const ushort4*)(pbase + (size_t)j * NGROUP * O_SZ);
        Pr[j][0] = h2f(pv.x);
        Pr[j][1] = h2f(pv.y);
        Pr[j][2] = h2f(pv.z);
        Pr[j][3] = h2f(pv.w);
    }

    float logit[RPT];
    #pragma unroll
    for (int j = 0; j < RPT; ++j) logit[j] = 0.0f;

    float vq[4];

    for (int it = 0; it < 3; ++it) {
        const int pb = it & 1;
        float sa0 = 0.f, sa1 = 0.f, sa2 = 0.f, sa3 = 0.f, zp = 0.f;
        #pragma unroll
        for (int j = 0; j < RPT; ++j) {
            const float e = __expf(logit[j]);
            zp += e;
            sa0 = fmaf(e, Pr[j][0], sa0);
            sa1 = fmaf(e, Pr[j][1], sa1);
            sa2 = fmaf(e, Pr[j][2], sa2);
            sa3 = fmaf(e, Pr[j][3], sa3);
        }
        #pragma unroll
        for (int m = 4; m <= 32; m <<= 1) {
            sa0 += __shfl_xor(sa0, m, 64);
            sa1 += __shfl_xor(sa1, m, 64);
            sa2 += __shfl_xor(sa2, m, 64);
            sa3 += __shfl_xor(sa3, m, 64);
            zp  += __shfl_xor(zp,  m, 64);
        }
        if (lane < 4) red_s[pb][wid][lane] = make_float4(sa0, sa1, sa2, sa3);
        if (lane == 0) red_z[pb][wid] = zp;
        __syncthreads();                       // the ONLY barrier this iter

        float4 sf = red_s[pb][0][q];
        float Z = red_z[pb][0];
        #pragma unroll
        for (int ww = 1; ww < NW; ++ww) {
            const float4 rr = red_s[pb][ww][q];
            sf.x += rr.x; sf.y += rr.y; sf.z += rr.z; sf.w += rr.w;
            Z += red_z[pb][ww];
        }

        const float invZ = 1.0f / Z;
        const float u0 = sf.x * invZ, u1 = sf.y * invZ,
                    u2 = sf.z * invZ, u3 = sf.w * invZ;
        float nq = u0*u0 + u1*u1 + u2*u2 + u3*u3;
        nq += __shfl_xor(nq, 1, 64);
        nq += __shfl_xor(nq, 2, 64);
        const float scale = nq / ((1.0f + nq) * sqrtf(nq));
        vq[0] = scale * u0; vq[1] = scale * u1;
        vq[2] = scale * u2; vq[3] = scale * u3;

        if (it < 2) {
            #pragma unroll
            for (int j = 0; j < RPT; ++j) {
                float d = Pr[j][0]*vq[0] + Pr[j][1]*vq[1]
                        + Pr[j][2]*vq[2] + Pr[j][3]*vq[3];
                d += __shfl_xor(d, 1, 64);
                d += __shfl_xor(d, 2, 64);
                logit[j] += d;
            }
        }
    }

    if (t < 4) {
        float* op = out + ((size_t)b * C_CAPS + c) * O_SZ + q * 4;
        *(float4*)op = make_float4(vq[0], vq[1], vq[2], vq[3]);
    }
}

// ---------------- fallback: v10 fused single kernel (72.5us, proven) ----------------
__global__ __launch_bounds__(T2, 1) void capsule_fused_kernel(
    const float* __restrict__ x,
    const float* __restrict__ w,
    float* __restrict__ out)
{
    const int c = blockIdx.x >> 8;
    const int b = blockIdx.x & 255;
    const int t = (int)threadIdx.x;
    const int lane = t & 63;
    const int wid = t >> 6;
    const int q = t & 3;
    const int g = t >> 2;

    __shared__ float4 red_s[NW][4];
    __shared__ float  red_z[NW];
    __shared__ float4 s_fin[4];
    __shared__ float  z_fin;

    float Pf[RPT][4];
    const float* xbase = x + ((size_t)b * R_SZ + g) * I_SZ;
    const float* wbase = w + ((size_t)c * R_SZ + g) * (I_SZ * O_SZ) + q * 4;
    const size_t xstep = (size_t)NGROUP * I_SZ;
    const size_t wstep = (size_t)NGROUP * I_SZ * O_SZ;

    float4 xc0 = *(const float4*)(xbase);
    float4 xc1 = *(const float4*)(xbase + 4);
    float4 wc[8];
    #pragma unroll
    for (int i = 0; i < I_SZ; ++i) wc[i] = *(const float4*)(wbase + i * O_SZ);

    #pragma unroll
    for (int j = 0; j < RPT; ++j) {
        float4 xn0, xn1, wn[8];
        if (j < RPT - 1) {
            const float* xp = xbase + (j + 1) * xstep;
            const float* wp = wbase + (j + 1) * wstep;
            xn0 = *(const float4*)(xp);
            xn1 = *(const float4*)(xp + 4);
            #pragma unroll
            for (int i = 0; i < I_SZ; ++i) wn[i] = *(const float4*)(wp + i * O_SZ);
        }
        const float xi[I_SZ] = {xc0.x, xc0.y, xc0.z, xc0.w,
                                xc1.x, xc1.y, xc1.z, xc1.w};
        float a0 = 0.f, a1 = 0.f, a2 = 0.f, a3 = 0.f;
        #pragma unroll
        for (int i = 0; i < I_SZ; ++i) {
            a0 = fmaf(xi[i], wc[i].x, a0);
            a1 = fmaf(xi[i], wc[i].y, a1);
            a2 = fmaf(xi[i], wc[i].z, a2);
            a3 = fmaf(xi[i], wc[i].w, a3);
        }
        Pf[j][0] = a0; Pf[j][1] = a1; Pf[j][2] = a2; Pf[j][3] = a3;
        if (j < RPT - 1) {
            xc0 = xn0; xc1 = xn1;
            #pragma unroll
            for (int i = 0; i < I_SZ; ++i) wc[i] = wn[i];
        }
    }

    float logit[RPT];
    #pragma unroll
    for (int j = 0; j < RPT; ++j) logit[j] = 0.0f;
    float vq[4];

    for (int it = 0; it < 3; ++it) {
        float sa0 = 0.f, sa1 = 0.f, sa2 = 0.f, sa3 = 0.f, zp = 0.f;
        #pragma unroll
        for (int j = 0; j < RPT; ++j) {
            const float e = __expf(logit[j]);
            zp += e;
            sa0 = fmaf(e, Pf[j][0], sa0);
            sa1 = fmaf(e, Pf[j][1], sa1);
            sa2 = fmaf(e, Pf[j][2], sa2);
            sa3 = fmaf(e, Pf[j][3], sa3);
        }
        #pragma unroll
        for (int m = 4; m <= 32; m <<= 1) {
            sa0 += __shfl_xor(sa0, m, 64);
            sa1 += __shfl_xor(sa1, m, 64);
            sa2 += __shfl_xor(sa2, m, 64);
            sa3 += __shfl_xor(sa3, m, 64);
            zp  += __shfl_xor(zp,  m, 64);
        }
        if (lane < 4) red_s[wid][lane] = make_float4(sa0, sa1, sa2, sa3);
        if (lane == 0) red_z[wid] = zp;
        __syncthreads();
        if (t < 4) {
            float4 a = red_s[0][t];
            #pragma unroll
            for (int ww = 1; ww < NW; ++ww) {
                const float4 rr = red_s[ww][t];
                a.x += rr.x; a.y += rr.y; a.z += rr.z; a.w += rr.w;
            }
            s_fin[t] = a;
        }
        if (t == 4) {
            float zz = red_z[0];
            #pragma unroll
            for (int ww = 1; ww < NW; ++ww) zz += red_z[ww];
            z_fin = zz;
        }
        __syncthreads();
        const float invZ = 1.0f / z_fin;
        const float4 sf = s_fin[q];
        const float u0 = sf.x * invZ, u1 = sf.y * invZ,
                    u2 = sf.z * invZ, u3 = sf.w * invZ;
        float nq = u0*u0 + u1*u1 + u2*u2 + u3*u3;
        nq += __shfl_xor(nq, 1, 64);
        nq += __shfl_xor(nq, 2, 64);
        const float scale = nq / ((1.0f + nq) * sqrtf(nq));
        vq[0] = scale * u0; vq[1] = scale * u1;
        vq[2] = scale * u2; vq[3] = scale * u3;
        if (it < 2) {
            #pragma unroll
            for (int j = 0; j < RPT; ++j) {
                float d = Pf[j][0]*vq[0] + Pf[j][1]*vq[1]
                        + Pf[j][2]*vq[2] + Pf[j][3]*vq[3];
                d += __shfl_xor(d, 1, 64);
                d += __shfl_xor(d, 2, 64);
                logit[j] += d;
            }
        }
    }

    if (t < 4) {
        float* op = out + ((size_t)b * C_CAPS + c) * O_SZ + q * 4;
        *(float4*)op = make_float4(vq[0], vq[1], vq[2], vq[3]);
    }
}

extern "C" void kernel_launch(void* const* d_in, const int* in_sizes, int n_in,
                              void* d_out, int out_size, void* d_ws, size_t ws_size,
                              hipStream_t stream) {
    const float* x = (const float*)d_in[0];
    const float* w = (const float*)d_in[1];
    float* out = (float*)d_out;

    const size_t pbytes = (size_t)C_CAPS * B_SZ * R_SZ * O_SZ * 2;  // 94.4 MB fp16
    if (ws_size >= pbytes) {
        unsigned short* P = (unsigned short*)d_ws;
        hipLaunchKernelGGL(priors_kernel, dim3(C_CAPS * 9 * 16), dim3(256),
                           0, stream, x, w, P);
        hipLaunchKernelGGL(routing_kernel, dim3(C_CAPS * B_SZ), dim3(T2),
                           0, stream, P, out);
    } else {
        hipLaunchKernelGGL(capsule_fused_kernel, dim3(C_CAPS * B_SZ), dim3(T2),
                           0, stream, x, w, out);
    }
}